// Round 6
// baseline (174.553 us; speedup 1.0000x reference)
//
#include <hip/hip_runtime.h>

typedef float f32x4 __attribute__((ext_vector_type(4)));
typedef short s16x8 __attribute__((ext_vector_type(8)));
typedef int   i32x2 __attribute__((ext_vector_type(2)));
typedef int   i32x4 __attribute__((ext_vector_type(4)));

#define DEV static __device__ __forceinline__

DEV short f2bf(float f) {
    unsigned u = __builtin_bit_cast(unsigned, f);
    u += 0x7FFFu + ((u >> 16) & 1u);
    return (short)(u >> 16);
}
DEV float bf2f(short s) {
    return __builtin_bit_cast(float, ((unsigned)(unsigned short)s) << 16);
}
DEV int cvtpk(float lo, float hi) {   // bf16(lo) in [15:0], bf16(hi) in [31:16]
    int r;
    asm("v_cvt_pk_bf16_f32 %0, %1, %2" : "=v"(r) : "v"(lo), "v"(hi));
    return r;
}
DEV float fexp2(float x) { float r; asm("v_exp_f32 %0, %1" : "=v"(r) : "v"(x)); return r; }
DEV float ffract(float x){ float r; asm("v_fract_f32 %0, %1" : "=v"(r) : "v"(x)); return r; }
DEV float fsin(float x)  { float r; asm("v_sin_f32 %0, %1" : "=v"(r) : "v"(x)); return r; }
DEV float fcos(float x)  { float r; asm("v_cos_f32 %0, %1" : "=v"(r) : "v"(x)); return r; }
DEV f32x4 mfma_bf16(s16x8 a, s16x8 b, f32x4 c) {
    asm("v_mfma_f32_16x16x32_bf16 %0, %1, %2, %0" : "+v"(c) : "v"(a), "v"(b));
    return c;
}
DEV f32x4 mfma16_bf16(i32x2 a, i32x2 b, f32x4 c) {
    asm("v_mfma_f32_16x16x16_bf16 %0, %1, %2, %0" : "+v"(c) : "v"(a), "v"(b));
    return c;
}
DEV void gl_lds16(const void* g, void* l) {
    __builtin_amdgcn_global_load_lds((const __attribute__((address_space(1))) unsigned*)g,
                                     (__attribute__((address_space(3))) unsigned*)l, 16, 0, 0);
}

// ---------------------------------------------------------------------------
// f32 -> bf16 convert: x (4M elems) + 4 weights (1M each).
// ---------------------------------------------------------------------------
__global__ __launch_bounds__(256) void conv_kernel(
    const float* __restrict__ x,
    const float* __restrict__ W0, const float* __restrict__ W1,
    const float* __restrict__ W2, const float* __restrict__ W3,
    short* __restrict__ xb,
    short* __restrict__ B0, short* __restrict__ B1,
    short* __restrict__ B2, short* __restrict__ B3)
{
    const int bid = blockIdx.x, tid = threadIdx.x;
    const float* src;
    short* dst;
    size_t off;
    if (bid < 2048) {
        src = x; dst = xb; off = (size_t)bid * 2048 + tid * 8;
    } else {
        int t = bid - 2048, wi = t >> 9;
        src = wi == 0 ? W0 : (wi == 1 ? W1 : (wi == 2 ? W2 : W3));
        dst = wi == 0 ? B0 : (wi == 1 ? B1 : (wi == 2 ? B2 : B3));
        off = (size_t)(t & 511) * 2048 + tid * 8;
    }
    f32x4 v0 = *(const f32x4*)(src + off);
    f32x4 v1 = *(const f32x4*)(src + off + 4);
    s16x8 o;
    #pragma unroll
    for (int e = 0; e < 4; e++) { o[e] = f2bf(v0[e]); o[4 + e] = f2bf(v1[e]); }
    *(s16x8*)(dst + off) = o;
}

// ---------------------------------------------------------------------------
// m97-structure GEMM: C[M][N] = A[M][1024] * B[N][1024]^T, all bf16 inputs.
// ROPE=1: fused rope in epilogue for z<=1 (Q gets log2(e)/8 fold), z==2 plain.
// ---------------------------------------------------------------------------
template<int OUT_BF16, int ROPE>
__global__ __launch_bounds__(256) void gemm128(
    const short* __restrict__ A,
    const short* __restrict__ Bq, const short* __restrict__ Bk, const short* __restrict__ Bv,
    void* __restrict__ Cq, void* __restrict__ Ck, void* __restrict__ Cv,
    const int* __restrict__ posp)
{
    constexpr int KD = 1024, ND = 1024;
    __shared__ __align__(16) short As[128 * 32];
    __shared__ __align__(16) short Bs[128 * 32];
    const int n0 = blockIdx.x * 128, m0 = blockIdx.y * 128;
    const int zz = blockIdx.z;
    const short* B = zz == 0 ? Bq : (zz == 1 ? Bk : Bv);
    void* C       = zz == 0 ? Cq : (zz == 1 ? Ck : Cv);
    const int tid = threadIdx.x;
    const int lane = tid & 63, w = tid >> 6, g = lane >> 4, c = lane & 15;
    const int wm = w >> 1, wn = w & 1;

    const int swz = (tid & 3) ^ ((tid >> 3) & 3);
    const short* a0 = A + (size_t)(m0 + (tid >> 2)) * KD + 8 * swz;
    const short* a1 = a0 + (size_t)64 * KD;
    const short* b0 = B + (size_t)(n0 + (tid >> 2)) * KD + 8 * swz;
    const short* b1 = b0 + (size_t)64 * KD;
    char* ldsA = (char*)As + w * 1024;
    char* ldsB = (char*)Bs + w * 1024;

    int aoff[4], boff[4];
    #pragma unroll
    for (int i = 0; i < 4; i++) {
        int ar = wm * 64 + i * 16 + c;
        aoff[i] = ar * 64 + (g ^ ((ar >> 1) & 3)) * 16;
        int br = wn * 64 + i * 16 + c;
        boff[i] = br * 64 + (g ^ ((br >> 1) & 3)) * 16;
    }

    f32x4 acc[4][4] = {};

    for (int k0 = 0; k0 < KD; k0 += 32) {
        __syncthreads();
        gl_lds16(a0 + k0, ldsA);
        gl_lds16(a1 + k0, ldsA + 4096);
        gl_lds16(b0 + k0, ldsB);
        gl_lds16(b1 + k0, ldsB + 4096);
        __syncthreads();
        s16x8 af[4], bf[4];
        #pragma unroll
        for (int i = 0; i < 4; i++) af[i] = *(const s16x8*)((const char*)As + aoff[i]);
        #pragma unroll
        for (int j = 0; j < 4; j++) bf[j] = *(const s16x8*)((const char*)Bs + boff[j]);
        #pragma unroll
        for (int i = 0; i < 4; i++)
            #pragma unroll
            for (int j = 0; j < 4; j++)
                acc[i][j] = mfma_bf16(af[i], bf[j], acc[i][j]);
    }

    // fused rope on Q/K outputs: rotate pairs (even,odd col) within each head.
    // Lane pair (c, c^1) holds the (x1, x2) pair; exchange via shfl_xor(1).
    if (ROPE && zz <= 1) {
        const float ps = (zz == 0) ? 0.18033688011112042f : 1.0f;  // log2(e)/8 on Q
        #pragma unroll
        for (int j = 0; j < 4; j++) {
            int col = n0 + wn * 64 + j * 16 + c;
            // inv_freq/(2pi) = 2^(-p0*log2(1e5)/32) / (2pi)
            float invf = fexp2(-(float)((col & 63) >> 1) * 0.51905126482615036f)
                       * 0.15915494309189535f;
            float ssign = (col & 1) ? 1.f : -1.f;
            #pragma unroll
            for (int i = 0; i < 4; i++)
                #pragma unroll
                for (int r = 0; r < 4; r++) {
                    int row = m0 + wm * 64 + i * 16 + 4 * g + r;
                    float fp = (float)posp[row];
                    float fr = ffract(fp * invf);
                    float sn = fsin(fr) * ps, cs = fcos(fr) * ps;
                    float own = acc[i][j][r];
                    float oth = __shfl_xor(own, 1);
                    acc[i][j][r] = own * cs + oth * (ssign * sn);
                }
        }
    }

    #pragma unroll
    for (int i = 0; i < 4; i++)
        #pragma unroll
        for (int j = 0; j < 4; j++)
            #pragma unroll
            for (int r = 0; r < 4; r++) {
                int row = m0 + wm * 64 + i * 16 + 4 * g + r;
                int col = n0 + wn * 64 + j * 16 + c;
                float v = acc[i][j][r];
                if (OUT_BF16) ((short*)C)[(size_t)row * ND + col] = f2bf(v);
                else          ((float*)C)[(size_t)row * ND + col] = v;
            }
}

// ---------------------------------------------------------------------------
// fallback GEMM (f32 inputs, 64x64 tile) -- used if ws_size too small.
// ---------------------------------------------------------------------------
template<int A_BF16, int OUT_BF16>
__global__ __launch_bounds__(256) void gemm_bt(
    const void* __restrict__ Ap,
    const float* __restrict__ B0, const float* __restrict__ B1, const float* __restrict__ B2,
    void* __restrict__ C0, void* __restrict__ C1, void* __restrict__ C2)
{
    constexpr int KD = 1024, ND = 1024;
    __shared__ short As[64][40];
    __shared__ short Bs[64][40];
    const int n0 = blockIdx.x * 64, m0 = blockIdx.y * 64;
    const float* Bw = blockIdx.z == 0 ? B0 : (blockIdx.z == 1 ? B1 : B2);
    void* Cw       = blockIdx.z == 0 ? C0 : (blockIdx.z == 1 ? C1 : C2);
    const int tid = threadIdx.x;
    const int lane = tid & 63, w = tid >> 6, g = lane >> 4, c = lane & 15;
    const int wm = w >> 1, wn = w & 1;
    const int sr = tid >> 2, scc = (tid & 3) * 8;

    f32x4 acc[2][2] = {};

    for (int k0 = 0; k0 < KD; k0 += 32) {
        __syncthreads();
        if (A_BF16) {
            *(s16x8*)&As[sr][scc] =
                *(const s16x8*)((const short*)Ap + (size_t)(m0 + sr) * KD + k0 + scc);
        } else {
            const float* ap = (const float*)Ap + (size_t)(m0 + sr) * KD + k0 + scc;
            f32x4 va = *(const f32x4*)ap, vb = *(const f32x4*)(ap + 4);
            s16x8 av;
            #pragma unroll
            for (int e = 0; e < 4; e++) { av[e] = f2bf(va[e]); av[4 + e] = f2bf(vb[e]); }
            *(s16x8*)&As[sr][scc] = av;
        }
        {
            const float* bp = Bw + (size_t)(n0 + sr) * KD + k0 + scc;
            f32x4 va = *(const f32x4*)bp, vb = *(const f32x4*)(bp + 4);
            s16x8 bv;
            #pragma unroll
            for (int e = 0; e < 4; e++) { bv[e] = f2bf(va[e]); bv[4 + e] = f2bf(vb[e]); }
            *(s16x8*)&Bs[sr][scc] = bv;
        }
        __syncthreads();
        s16x8 af[2], bfv[2];
        #pragma unroll
        for (int i = 0; i < 2; i++) af[i]  = *(const s16x8*)&As[wm * 32 + i * 16 + c][8 * g];
        #pragma unroll
        for (int j = 0; j < 2; j++) bfv[j] = *(const s16x8*)&Bs[wn * 32 + j * 16 + c][8 * g];
        #pragma unroll
        for (int i = 0; i < 2; i++)
            #pragma unroll
            for (int j = 0; j < 2; j++)
                acc[i][j] = mfma_bf16(af[i], bfv[j], acc[i][j]);
    }

    #pragma unroll
    for (int i = 0; i < 2; i++)
        #pragma unroll
        for (int j = 0; j < 2; j++)
            #pragma unroll
            for (int r = 0; r < 4; r++) {
                int row = m0 + wm * 32 + i * 16 + 4 * g + r;
                int col = n0 + wn * 32 + j * 16 + c;
                float v = acc[i][j][r];
                if (OUT_BF16) ((short*)Cw)[(size_t)row * ND + col] = f2bf(v);
                else          ((float*)Cw)[(size_t)row * ND + col] = v;
            }
}

// ---------------------------------------------------------------------------
// standalone RoPE (fallback tier only)
// ---------------------------------------------------------------------------
__global__ __launch_bounds__(256) void rope_kernel(short* Q, short* K, const int* __restrict__ posp)
{
    const int t = blockIdx.x * 256 + threadIdx.x;
    const int isK = blockIdx.y;
    short* ptr = isK ? K : Q;
    const float postscale = isK ? 1.0f : 0.18033688011112042f;  // log2(e)/8
    const int idx  = t * 8;
    const int srow = idx >> 10;
    const int dd   = (idx & 1023) & 63;
    const int p0   = dd >> 1;
    const float fp = (float)posp[srow];
    s16x8 v = *(s16x8*)(ptr + idx);
    s16x8 o;
    #pragma unroll
    for (int pr = 0; pr < 4; pr++) {
        float ex  = fexp2(-(float)(p0 + pr) * 0.51905126482615036f);
        float ang = fp * ex * 0.15915494309189535f;
        float fr  = ffract(ang);
        float sn  = fsin(fr) * postscale;
        float cs  = fcos(fr) * postscale;
        float x1 = bf2f(v[2 * pr]), x2 = bf2f(v[2 * pr + 1]);
        o[2 * pr]     = f2bf(x1 * cs - x2 * sn);
        o[2 * pr + 1] = f2bf(x1 * sn + x2 * cs);
    }
    *(s16x8*)(ptr + idx) = o;
}

// ---------------------------------------------------------------------------
// Flash attention v6 = v5 structure + uniform paired work.
// Grid (32, 16, 1+SPLIT): block handles qb in {bx, 63-bx} sequentially,
// kv tiles strided by 1+SPLIT starting at z -> every block ~32.5 (SPLIT) or
// 65 (no split) tile-iters: uniform, all blocks co-resident, no drain tail.
// Fixed-m softmax (scores pre-scaled to log2 domain); P stays in registers
// (16x16x16 PV); K staged via global_load_lds w/ pre-swizzled source.
// ---------------------------------------------------------------------------
template<int SPLIT>
__global__ __launch_bounds__(256, 5) void attn_kernel(
    const short* __restrict__ Q, const short* __restrict__ K,
    const short* __restrict__ V, short* __restrict__ O0,
    short* __restrict__ O1, float* __restrict__ Lf)
{
    constexpr int D = 1024;
    constexpr int ST = 1 + SPLIT;
    const int bx = blockIdx.x;
    const int h = blockIdx.y, hc = h * 64;
    const int z = SPLIT ? (int)blockIdx.z : 0;
    short* O = (SPLIT && z) ? O1 : O0;
    const int tid = threadIdx.x;
    const int w = tid >> 6, lane = tid & 63, g = lane >> 4, c = lane & 15;

    __shared__ __align__(16) int Kl[2][64 * 32];  // row-major 64x64 bf16, chunk^=(row&7)
    __shared__ __align__(16) int Vl[2][64][32];   // [d][kvp] dwords, chunk^=(d&7)

    const int krow_l = lane >> 3;
    const int kchunk = (lane & 7) ^ krow_l;
    const short* Kpre = K + hc + (size_t)(w * 16 + krow_l) * D + kchunk * 8;
    char* kdst0 = (char*)&Kl[0][0] + w * 16 * 128;
    char* kdst1 = (char*)&Kl[1][0] + w * 16 * 128;

    const int vkvp = tid & 31;
    const int vd0 = (tid >> 5) * 8;
    const short* Vpre = V + hc + (size_t)(2 * vkvp) * D + vd0;

    int koff0[4], koff1[4];
    #pragma unroll
    for (int t = 0; t < 4; t++) {
        int row = t * 16 + c;
        koff0[t] = row * 128 + ((g) ^ (row & 7)) * 16;
        koff1[t] = row * 128 + ((4 + g) ^ (row & 7)) * 16;
    }

    for (int pi = 0; pi < 2; pi++) {
        const int qb = pi ? 63 - bx : bx;
        const int qrow = qb * 64 + w * 16 + c;
        const short* qp = Q + (size_t)qrow * D + hc + 8 * g;
        const s16x8 bq0 = *(const s16x8*)qp;
        const s16x8 bq1 = *(const s16x8*)(qp + 32);

        f32x4 acc[4] = {};
        float l = 0.f;
        const int nkb = qb + 1;

        __syncthreads();   // prev pi's LDS reads fully done
        s16x8 vs0, vs1;
        if (z < nkb) {     // prologue: stage tile kb=z into buffer 0
            gl_lds16(Kpre + (size_t)(z * 64) * D, kdst0);
            gl_lds16(Kpre + (size_t)(z * 64 + 8) * D, kdst0 + 8 * 128);
            const short* vp = Vpre + (size_t)(z * 64) * D;
            vs0 = *(const s16x8*)vp;
            vs1 = *(const s16x8*)(vp + D);
        }

        int cur = 0;
        for (int kb = z; kb < nkb; kb += ST, cur ^= 1) {
            // pack V (tile kb) into Vl[cur]
            #pragma unroll
            for (int e = 0; e < 8; e++) {
                unsigned dw = (unsigned)(unsigned short)vs0[e] | ((unsigned)(unsigned short)vs1[e] << 16);
                Vl[cur][vd0 + e][vkvp ^ (4 * e)] = (int)dw;
            }
            asm volatile("s_waitcnt vmcnt(0)" ::: "memory");   // own K gl_lds landed
            __syncthreads();

            // issue next-tile staging (targets buffer cur^1)
            const bool more = (kb + ST) < nkb;
            if (more) {
                const int kb1 = kb + ST;
                char* kd = cur ? kdst0 : kdst1;
                gl_lds16(Kpre + (size_t)(kb1 * 64) * D, kd);
                gl_lds16(Kpre + (size_t)(kb1 * 64 + 8) * D, kd + 8 * 128);
                const short* vp = Vpre + (size_t)(kb1 * 64) * D;
                vs0 = *(const s16x8*)vp;
                vs1 = *(const s16x8*)(vp + D);
            }

            // QK^T (swapped): st[t][i] = S[kv = kb*64+t*16+4g+i][q = qrow]
            const char* Kb = (const char*)&Kl[cur][0];
            f32x4 st[4];
            __builtin_amdgcn_s_setprio(1);
            #pragma unroll
            for (int t = 0; t < 4; t++) {
                s16x8 a0 = *(const s16x8*)(Kb + koff0[t]);
                s16x8 a1 = *(const s16x8*)(Kb + koff1[t]);
                f32x4 zf = {};
                zf = mfma_bf16(a0, bq0, zf);
                zf = mfma_bf16(a1, bq1, zf);
                st[t] = zf;
            }
            __builtin_amdgcn_s_setprio(0);

            // p = 2^s (fixed m=0); mask only diagonal tile; l lane-local
            float p[16];
            if (kb == qb) {
                #pragma unroll
                for (int t = 0; t < 4; t++)
                    #pragma unroll
                    for (int i = 0; i < 4; i++) {
                        int kv = kb * 64 + t * 16 + 4 * g + i;
                        float e = fexp2(st[t][i]);
                        if (kv > qrow) e = 0.f;
                        p[t * 4 + i] = e;
                        l += e;
                    }
            } else {
                #pragma unroll
                for (int t = 0; t < 4; t++)
                    #pragma unroll
                    for (int i = 0; i < 4; i++) {
                        float e = fexp2(st[t][i]);
                        p[t * 4 + i] = e;
                        l += e;
                    }
            }

            // P fragments stay in registers: pd[t] = P[q=c][kv=t*16+4g..+3]
            i32x2 pd[4];
            #pragma unroll
            for (int t = 0; t < 4; t++) {
                pd[t][0] = cvtpk(p[t * 4 + 0], p[t * 4 + 1]);
                pd[t][1] = cvtpk(p[t * 4 + 2], p[t * 4 + 3]);
            }

            // PV via 16x16x16: acc[jt][q=4g+i][d=jt*16+c] += P[q][kv16]*V[kv16][d]
            __builtin_amdgcn_s_setprio(1);
            #pragma unroll
            for (int t = 0; t < 4; t++) {
                #pragma unroll
                for (int jt = 0; jt < 4; jt++) {
                    i32x2 vb = *(const i32x2*)&Vl[cur][jt * 16 + c][(t * 8 + 2 * g) ^ (4 * (c & 7))];
                    acc[jt] = mfma16_bf16(pd[t], vb, acc[jt]);
                }
            }
            __builtin_amdgcn_s_setprio(0);
        }

        // finalize: reduce l across g-groups (all lanes end with l(q=c))
        float lsum = l + __shfl_xor(l, 16);
        lsum += __shfl_xor(lsum, 32);
        if (SPLIT && lane < 16) {
            float Lv = (lsum > 0.f) ? __log2f(lsum) : -1e30f;
            Lf[(size_t)(z * 16 + h) * 4096 + (qb * 64 + w * 16 + lane)] = Lv;
        }
        float linv[4];
        #pragma unroll
        for (int i = 0; i < 4; i++) {
            float ls = __shfl(lsum, 4 * g + i);
            linv[i] = (ls > 0.f) ? 1.f / ls : 0.f;
        }
        #pragma unroll
        for (int jt = 0; jt < 4; jt++)
            #pragma unroll
            for (int i = 0; i < 4; i++) {
                int r = qb * 64 + w * 16 + 4 * g + i;
                O[(size_t)r * D + hc + jt * 16 + c] = f2bf(acc[jt][i] * linv[i]);
            }
    }
}

// ---------------------------------------------------------------------------
// Combine split-kv partials: Aw = w0*Aw + w1*P1, w_i = softmax over L.
// ---------------------------------------------------------------------------
__global__ __launch_bounds__(256) void combine_kernel(
    short* __restrict__ Aw, const short* __restrict__ P1, const float* __restrict__ Lf)
{
    const int t = blockIdx.x * 256 + threadIdx.x;
    const int idx = t * 8;
    const int row = idx >> 10, col = idx & 1023, h = col >> 6;
    float L0 = Lf[(size_t)h * 4096 + row];
    float L1 = Lf[(size_t)(16 + h) * 4096 + row];
    float LM = fmaxf(L0, L1);
    float w0 = fexp2(L0 - LM), w1 = fexp2(L1 - LM);
    float inv = 1.f / (w0 + w1);
    w0 *= inv; w1 *= inv;
    s16x8 a = *(s16x8*)(Aw + idx);
    s16x8 b = *(const s16x8*)(P1 + idx);
    s16x8 o;
    #pragma unroll
    for (int e = 0; e < 8; e++)
        o[e] = f2bf(w0 * bf2f(a[e]) + w1 * bf2f(b[e]));
    *(s16x8*)(Aw + idx) = o;
}

// ---------------------------------------------------------------------------
extern "C" void kernel_launch(void* const* d_in, const int* in_sizes, int n_in,
                              void* d_out, int out_size, void* d_ws, size_t ws_size,
                              hipStream_t stream)
{
    const float* x  = (const float*)d_in[0];
    const float* Wq = (const float*)d_in[1];
    const float* Wk = (const float*)d_in[2];
    const float* Wv = (const float*)d_in[3];
    const float* Wo = (const float*)d_in[4];
    const int*  pos = (const int*)d_in[5];
    float* out = (float*)d_out;

    const size_t SD = (size_t)4096 * 1024;
    const size_t WSZ = (size_t)1024 * 1024;
    short* Qw = (short*)d_ws;
    short* Kw = Qw + SD;
    short* Vw = Kw + SD;
    short* Aw = Vw + SD;

    const size_t need_A = (5 * SD + 4 * WSZ) * sizeof(short) + 2 * 16 * 4096 * sizeof(float);
    const size_t need_B = (4 * SD + 4 * WSZ) * sizeof(short);

    if (ws_size >= need_A) {
        short* P1  = Aw + SD;
        short* xb  = Aw;
        short* Wqb = P1 + SD;
        short* Wkb = Wqb + WSZ;
        short* Wvb = Wkb + WSZ;
        short* Wob = Wvb + WSZ;
        float* Lf  = (float*)(Wob + WSZ);
        conv_kernel<<<4096, 256, 0, stream>>>(x, Wq, Wk, Wv, Wo, xb, Wqb, Wkb, Wvb, Wob);
        gemm128<1, 1><<<dim3(8, 32, 3), 256, 0, stream>>>(xb, Wqb, Wkb, Wvb, Qw, Kw, Vw, pos);
        attn_kernel<1><<<dim3(32, 16, 2), 256, 0, stream>>>(Qw, Kw, Vw, Aw, P1, Lf);
        combine_kernel<<<2048, 256, 0, stream>>>(Aw, P1, Lf);
        gemm128<0, 0><<<dim3(8, 32, 1), 256, 0, stream>>>(Aw, Wob, Wob, Wob, out, out, out, pos);
    } else if (ws_size >= need_B) {
        short* xb  = Aw;
        short* Wqb = Aw + SD;
        short* Wkb = Wqb + WSZ;
        short* Wvb = Wkb + WSZ;
        short* Wob = Wvb + WSZ;
        conv_kernel<<<4096, 256, 0, stream>>>(x, Wq, Wk, Wv, Wo, xb, Wqb, Wkb, Wvb, Wob);
        gemm128<1, 1><<<dim3(8, 32, 3), 256, 0, stream>>>(xb, Wqb, Wkb, Wvb, Qw, Kw, Vw, pos);
        attn_kernel<0><<<dim3(32, 16, 1), 256, 0, stream>>>(Qw, Kw, Vw, Aw, Aw, nullptr);
        gemm128<0, 0><<<dim3(8, 32, 1), 256, 0, stream>>>(Aw, Wob, Wob, Wob, out, out, out, pos);
    } else {
        gemm_bt<0, 1><<<dim3(16, 64, 3), 256, 0, stream>>>(x, Wq, Wk, Wv, Qw, Kw, Vw);
        rope_kernel<<<dim3(2048, 2), 256, 0, stream>>>(Qw, Kw, pos);
        attn_kernel<0><<<dim3(32, 16, 1), 256, 0, stream>>>(Qw, Kw, Vw, Aw, Aw, nullptr);
        gemm_bt<1, 0><<<dim3(16, 64, 1), 256, 0, stream>>>(Aw, Wo, Wo, Wo, out, out, out);
    }
}

// Round 7
// 139.006 us; speedup vs baseline: 1.2557x; 1.2557x over previous
//
#include <hip/hip_runtime.h>

typedef float f32x4 __attribute__((ext_vector_type(4)));
typedef short s16x8 __attribute__((ext_vector_type(8)));
typedef int   i32x2 __attribute__((ext_vector_type(2)));
typedef int   i32x4 __attribute__((ext_vector_type(4)));

#define DEV static __device__ __forceinline__

DEV short f2bf(float f) {
    unsigned u = __builtin_bit_cast(unsigned, f);
    u += 0x7FFFu + ((u >> 16) & 1u);
    return (short)(u >> 16);
}
DEV float bf2f(short s) {
    return __builtin_bit_cast(float, ((unsigned)(unsigned short)s) << 16);
}
DEV int cvtpk(float lo, float hi) {   // bf16(lo) in [15:0], bf16(hi) in [31:16]
    int r;
    asm("v_cvt_pk_bf16_f32 %0, %1, %2" : "=v"(r) : "v"(lo), "v"(hi));
    return r;
}
DEV float fexp2(float x) { float r; asm("v_exp_f32 %0, %1" : "=v"(r) : "v"(x)); return r; }
DEV float ffract(float x){ float r; asm("v_fract_f32 %0, %1" : "=v"(r) : "v"(x)); return r; }
DEV float fsin(float x)  { float r; asm("v_sin_f32 %0, %1" : "=v"(r) : "v"(x)); return r; }
DEV float fcos(float x)  { float r; asm("v_cos_f32 %0, %1" : "=v"(r) : "v"(x)); return r; }
DEV f32x4 mfma_bf16(s16x8 a, s16x8 b, f32x4 c) {
    asm("v_mfma_f32_16x16x32_bf16 %0, %1, %2, %0" : "+v"(c) : "v"(a), "v"(b));
    return c;
}
DEV f32x4 mfma16_bf16(i32x2 a, i32x2 b, f32x4 c) {
    asm("v_mfma_f32_16x16x16_bf16 %0, %1, %2, %0" : "+v"(c) : "v"(a), "v"(b));
    return c;
}
DEV void gl_lds16(const void* g, void* l) {
    __builtin_amdgcn_global_load_lds((const __attribute__((address_space(1))) unsigned*)g,
                                     (__attribute__((address_space(3))) unsigned*)l, 16, 0, 0);
}

// ---------------------------------------------------------------------------
// f32 -> bf16 convert: x (4M elems) + 4 weights (1M each).
// ---------------------------------------------------------------------------
__global__ __launch_bounds__(256) void conv_kernel(
    const float* __restrict__ x,
    const float* __restrict__ W0, const float* __restrict__ W1,
    const float* __restrict__ W2, const float* __restrict__ W3,
    short* __restrict__ xb,
    short* __restrict__ B0, short* __restrict__ B1,
    short* __restrict__ B2, short* __restrict__ B3)
{
    const int bid = blockIdx.x, tid = threadIdx.x;
    const float* src;
    short* dst;
    size_t off;
    if (bid < 2048) {
        src = x; dst = xb; off = (size_t)bid * 2048 + tid * 8;
    } else {
        int t = bid - 2048, wi = t >> 9;
        src = wi == 0 ? W0 : (wi == 1 ? W1 : (wi == 2 ? W2 : W3));
        dst = wi == 0 ? B0 : (wi == 1 ? B1 : (wi == 2 ? B2 : B3));
        off = (size_t)(t & 511) * 2048 + tid * 8;
    }
    f32x4 v0 = *(const f32x4*)(src + off);
    f32x4 v1 = *(const f32x4*)(src + off + 4);
    s16x8 o;
    #pragma unroll
    for (int e = 0; e < 4; e++) { o[e] = f2bf(v0[e]); o[4 + e] = f2bf(v1[e]); }
    *(s16x8*)(dst + off) = o;
}

// ---------------------------------------------------------------------------
// m97-structure GEMM: C[M][N] = A[M][1024] * B[N][1024]^T, bf16 inputs.
// BM = 128 (4x4 frags/wave) or 64 (2x4 frags/wave, for small-M-tile grids).
// ROPE=1 (BM=128 only): fused rope epilogue, z<=1; Q gets log2(e)/8 fold.
// ---------------------------------------------------------------------------
template<int BM, int OUT_BF16, int ROPE>
__global__ __launch_bounds__(256) void gemm128(
    const short* __restrict__ A,
    const short* __restrict__ Bq, const short* __restrict__ Bk, const short* __restrict__ Bv,
    void* __restrict__ Cq, void* __restrict__ Ck, void* __restrict__ Cv,
    const int* __restrict__ posp)
{
    constexpr int KD = 1024, ND = 1024;
    constexpr int MI = BM / 32;                    // M-frags per wave
    __shared__ __align__(16) short As[BM * 32];
    __shared__ __align__(16) short Bs[128 * 32];
    const int n0 = blockIdx.x * 128, m0 = blockIdx.y * BM;
    const int zz = blockIdx.z;
    const short* B = zz == 0 ? Bq : (zz == 1 ? Bk : Bv);
    void* C       = zz == 0 ? Cq : (zz == 1 ? Ck : Cv);
    const int tid = threadIdx.x;
    const int lane = tid & 63, w = tid >> 6, g = lane >> 4, c = lane & 15;
    const int wm = w >> 1, wn = w & 1;

    const int swz = (tid & 3) ^ ((tid >> 3) & 3);
    const short* a0 = A + (size_t)(m0 + (tid >> 2)) * KD + 8 * swz;
    const short* a1 = a0 + (size_t)64 * KD;        // only used if BM==128
    const short* b0 = B + (size_t)(n0 + (tid >> 2)) * KD + 8 * swz;
    const short* b1 = b0 + (size_t)64 * KD;
    char* ldsA = (char*)As + w * 1024;
    char* ldsB = (char*)Bs + w * 1024;

    int aoff[MI], boff[4];
    #pragma unroll
    for (int i = 0; i < MI; i++) {
        int ar = wm * (BM / 2) + i * 16 + c;
        aoff[i] = ar * 64 + (g ^ ((ar >> 1) & 3)) * 16;
    }
    #pragma unroll
    for (int j = 0; j < 4; j++) {
        int br = wn * 64 + j * 16 + c;
        boff[j] = br * 64 + (g ^ ((br >> 1) & 3)) * 16;
    }

    f32x4 acc[MI][4] = {};

    for (int k0 = 0; k0 < KD; k0 += 32) {
        __syncthreads();
        gl_lds16(a0 + k0, ldsA);
        if (BM == 128) gl_lds16(a1 + k0, ldsA + 4096);
        gl_lds16(b0 + k0, ldsB);
        gl_lds16(b1 + k0, ldsB + 4096);
        __syncthreads();
        s16x8 af[MI], bf[4];
        #pragma unroll
        for (int i = 0; i < MI; i++) af[i] = *(const s16x8*)((const char*)As + aoff[i]);
        #pragma unroll
        for (int j = 0; j < 4; j++) bf[j] = *(const s16x8*)((const char*)Bs + boff[j]);
        #pragma unroll
        for (int i = 0; i < MI; i++)
            #pragma unroll
            for (int j = 0; j < 4; j++)
                acc[i][j] = mfma_bf16(af[i], bf[j], acc[i][j]);
    }

    // fused rope on Q/K outputs: rotate (even,odd col) pairs within each head.
    // Lane pair (c, c^1) holds (x1, x2); exchange via shfl_xor(1).
    if (ROPE && zz <= 1) {
        const float ps = (zz == 0) ? 0.18033688011112042f : 1.0f;  // log2(e)/8 on Q
        #pragma unroll
        for (int j = 0; j < 4; j++) {
            int col = n0 + wn * 64 + j * 16 + c;
            float invf = fexp2(-(float)((col & 63) >> 1) * 0.51905126482615036f)
                       * 0.15915494309189535f;
            float ssign = (col & 1) ? 1.f : -1.f;
            #pragma unroll
            for (int i = 0; i < MI; i++)
                #pragma unroll
                for (int r = 0; r < 4; r++) {
                    int row = m0 + wm * (BM / 2) + i * 16 + 4 * g + r;
                    float fp = (float)posp[row];
                    float fr = ffract(fp * invf);
                    float sn = fsin(fr) * ps, cs = fcos(fr) * ps;
                    float own = acc[i][j][r];
                    float oth = __shfl_xor(own, 1);
                    acc[i][j][r] = own * cs + oth * (ssign * sn);
                }
        }
    }

    #pragma unroll
    for (int i = 0; i < MI; i++)
        #pragma unroll
        for (int j = 0; j < 4; j++)
            #pragma unroll
            for (int r = 0; r < 4; r++) {
                int row = m0 + wm * (BM / 2) + i * 16 + 4 * g + r;
                int col = n0 + wn * 64 + j * 16 + c;
                float v = acc[i][j][r];
                if (OUT_BF16) ((short*)C)[(size_t)row * ND + col] = f2bf(v);
                else          ((float*)C)[(size_t)row * ND + col] = v;
            }
}

// ---------------------------------------------------------------------------
// fallback GEMM (f32 inputs, 64x64 tile) -- used if ws_size too small.
// ---------------------------------------------------------------------------
template<int A_BF16, int OUT_BF16>
__global__ __launch_bounds__(256) void gemm_bt(
    const void* __restrict__ Ap,
    const float* __restrict__ B0, const float* __restrict__ B1, const float* __restrict__ B2,
    void* __restrict__ C0, void* __restrict__ C1, void* __restrict__ C2)
{
    constexpr int KD = 1024, ND = 1024;
    __shared__ short As[64][40];
    __shared__ short Bs[64][40];
    const int n0 = blockIdx.x * 64, m0 = blockIdx.y * 64;
    const float* Bw = blockIdx.z == 0 ? B0 : (blockIdx.z == 1 ? B1 : B2);
    void* Cw       = blockIdx.z == 0 ? C0 : (blockIdx.z == 1 ? C1 : C2);
    const int tid = threadIdx.x;
    const int lane = tid & 63, w = tid >> 6, g = lane >> 4, c = lane & 15;
    const int wm = w >> 1, wn = w & 1;
    const int sr = tid >> 2, scc = (tid & 3) * 8;

    f32x4 acc[2][2] = {};

    for (int k0 = 0; k0 < KD; k0 += 32) {
        __syncthreads();
        if (A_BF16) {
            *(s16x8*)&As[sr][scc] =
                *(const s16x8*)((const short*)Ap + (size_t)(m0 + sr) * KD + k0 + scc);
        } else {
            const float* ap = (const float*)Ap + (size_t)(m0 + sr) * KD + k0 + scc;
            f32x4 va = *(const f32x4*)ap, vb = *(const f32x4*)(ap + 4);
            s16x8 av;
            #pragma unroll
            for (int e = 0; e < 4; e++) { av[e] = f2bf(va[e]); av[4 + e] = f2bf(vb[e]); }
            *(s16x8*)&As[sr][scc] = av;
        }
        {
            const float* bp = Bw + (size_t)(n0 + sr) * KD + k0 + scc;
            f32x4 va = *(const f32x4*)bp, vb = *(const f32x4*)(bp + 4);
            s16x8 bv;
            #pragma unroll
            for (int e = 0; e < 4; e++) { bv[e] = f2bf(va[e]); bv[4 + e] = f2bf(vb[e]); }
            *(s16x8*)&Bs[sr][scc] = bv;
        }
        __syncthreads();
        s16x8 af[2], bfv[2];
        #pragma unroll
        for (int i = 0; i < 2; i++) af[i]  = *(const s16x8*)&As[wm * 32 + i * 16 + c][8 * g];
        #pragma unroll
        for (int j = 0; j < 2; j++) bfv[j] = *(const s16x8*)&Bs[wn * 32 + j * 16 + c][8 * g];
        #pragma unroll
        for (int i = 0; i < 2; i++)
            #pragma unroll
            for (int j = 0; j < 2; j++)
                acc[i][j] = mfma_bf16(af[i], bfv[j], acc[i][j]);
    }

    #pragma unroll
    for (int i = 0; i < 2; i++)
        #pragma unroll
        for (int j = 0; j < 2; j++)
            #pragma unroll
            for (int r = 0; r < 4; r++) {
                int row = m0 + wm * 32 + i * 16 + 4 * g + r;
                int col = n0 + wn * 32 + j * 16 + c;
                float v = acc[i][j][r];
                if (OUT_BF16) ((short*)Cw)[(size_t)row * ND + col] = f2bf(v);
                else          ((float*)Cw)[(size_t)row * ND + col] = v;
            }
}

// ---------------------------------------------------------------------------
// standalone RoPE (fallback tier only)
// ---------------------------------------------------------------------------
__global__ __launch_bounds__(256) void rope_kernel(short* Q, short* K, const int* __restrict__ posp)
{
    const int t = blockIdx.x * 256 + threadIdx.x;
    const int isK = blockIdx.y;
    short* ptr = isK ? K : Q;
    const float postscale = isK ? 1.0f : 0.18033688011112042f;  // log2(e)/8
    const int idx  = t * 8;
    const int srow = idx >> 10;
    const int dd   = (idx & 1023) & 63;
    const int p0   = dd >> 1;
    const float fp = (float)posp[srow];
    s16x8 v = *(s16x8*)(ptr + idx);
    s16x8 o;
    #pragma unroll
    for (int pr = 0; pr < 4; pr++) {
        float ex  = fexp2(-(float)(p0 + pr) * 0.51905126482615036f);
        float ang = fp * ex * 0.15915494309189535f;
        float fr  = ffract(ang);
        float sn  = fsin(fr) * postscale;
        float cs  = fcos(fr) * postscale;
        float x1 = bf2f(v[2 * pr]), x2 = bf2f(v[2 * pr + 1]);
        o[2 * pr]     = f2bf(x1 * cs - x2 * sn);
        o[2 * pr + 1] = f2bf(x1 * sn + x2 * cs);
    }
    *(s16x8*)(ptr + idx) = o;
}

// ---------------------------------------------------------------------------
// Flash attention v7 = v6 + XCD-aware head pinning.
// SPLIT=1: 1D grid 1024; decode so ALL blocks of head h land on XCD h%8
// (consecutive dispatch ids round-robin XCDs): xcd=B&7, k=B>>3,
// h=xcd+8*(k>>6), r=k&63, bx=r&31, z=r>>5.  Per-XCD K/V working set =
// 2 heads = 4MB = L2 -> tile fetches become L2 hits.
// Each block: qb in {bx, 63-bx} sequentially, kv tiles z-strided by 2.
// Fixed-m softmax (log2-domain scores); P in registers (16x16x16 PV);
// K via global_load_lds w/ pre-swizzled source, double-buffered.
// ---------------------------------------------------------------------------
template<int SPLIT>
__global__ __launch_bounds__(256, 5) void attn_kernel(
    const short* __restrict__ Q, const short* __restrict__ K,
    const short* __restrict__ V, short* __restrict__ O0,
    short* __restrict__ O1, float* __restrict__ Lf)
{
    constexpr int D = 1024;
    constexpr int ST = 1 + SPLIT;
    int bx, h, z;
    if (SPLIT) {
        const int B = blockIdx.x;
        const int xcd = B & 7, k = B >> 3;
        h = xcd + 8 * (k >> 6);
        const int r = k & 63;
        bx = r & 31;
        z = r >> 5;
    } else {
        bx = blockIdx.x; h = blockIdx.y; z = 0;
    }
    const int hc = h * 64;
    short* O = (SPLIT && z) ? O1 : O0;
    const int tid = threadIdx.x;
    const int w = tid >> 6, lane = tid & 63, g = lane >> 4, c = lane & 15;

    __shared__ __align__(16) int Kl[2][64 * 32];  // row-major 64x64 bf16, chunk^=(row&7)
    __shared__ __align__(16) int Vl[2][64][32];   // [d][kvp] dwords, chunk^=(d&7)

    const int krow_l = lane >> 3;
    const int kchunk = (lane & 7) ^ krow_l;
    const short* Kpre = K + hc + (size_t)(w * 16 + krow_l) * D + kchunk * 8;
    char* kdst0 = (char*)&Kl[0][0] + w * 16 * 128;
    char* kdst1 = (char*)&Kl[1][0] + w * 16 * 128;

    const int vkvp = tid & 31;
    const int vd0 = (tid >> 5) * 8;
    const short* Vpre = V + hc + (size_t)(2 * vkvp) * D + vd0;

    int koff0[4], koff1[4];
    #pragma unroll
    for (int t = 0; t < 4; t++) {
        int row = t * 16 + c;
        koff0[t] = row * 128 + ((g) ^ (row & 7)) * 16;
        koff1[t] = row * 128 + ((4 + g) ^ (row & 7)) * 16;
    }

    for (int pi = 0; pi < 2; pi++) {
        const int qb = pi ? 63 - bx : bx;
        const int qrow = qb * 64 + w * 16 + c;
        const short* qp = Q + (size_t)qrow * D + hc + 8 * g;
        const s16x8 bq0 = *(const s16x8*)qp;
        const s16x8 bq1 = *(const s16x8*)(qp + 32);

        f32x4 acc[4] = {};
        float l = 0.f;
        const int nkb = qb + 1;

        __syncthreads();   // prev pi's LDS reads fully done
        s16x8 vs0, vs1;
        if (z < nkb) {     // prologue: stage tile kb=z into buffer 0
            gl_lds16(Kpre + (size_t)(z * 64) * D, kdst0);
            gl_lds16(Kpre + (size_t)(z * 64 + 8) * D, kdst0 + 8 * 128);
            const short* vp = Vpre + (size_t)(z * 64) * D;
            vs0 = *(const s16x8*)vp;
            vs1 = *(const s16x8*)(vp + D);
        }

        int cur = 0;
        for (int kb = z; kb < nkb; kb += ST, cur ^= 1) {
            // pack V (tile kb) into Vl[cur]
            #pragma unroll
            for (int e = 0; e < 8; e++) {
                unsigned dw = (unsigned)(unsigned short)vs0[e] | ((unsigned)(unsigned short)vs1[e] << 16);
                Vl[cur][vd0 + e][vkvp ^ (4 * e)] = (int)dw;
            }
            asm volatile("s_waitcnt vmcnt(0)" ::: "memory");   // own K gl_lds landed
            __syncthreads();

            // issue next-tile staging (targets buffer cur^1)
            const bool more = (kb + ST) < nkb;
            if (more) {
                const int kb1 = kb + ST;
                char* kd = cur ? kdst0 : kdst1;
                gl_lds16(Kpre + (size_t)(kb1 * 64) * D, kd);
                gl_lds16(Kpre + (size_t)(kb1 * 64 + 8) * D, kd + 8 * 128);
                const short* vp = Vpre + (size_t)(kb1 * 64) * D;
                vs0 = *(const s16x8*)vp;
                vs1 = *(const s16x8*)(vp + D);
            }

            // QK^T (swapped): st[t][i] = S[kv = kb*64+t*16+4g+i][q = qrow]
            const char* Kb = (const char*)&Kl[cur][0];
            f32x4 st[4];
            __builtin_amdgcn_s_setprio(1);
            #pragma unroll
            for (int t = 0; t < 4; t++) {
                s16x8 a0 = *(const s16x8*)(Kb + koff0[t]);
                s16x8 a1 = *(const s16x8*)(Kb + koff1[t]);
                f32x4 zf = {};
                zf = mfma_bf16(a0, bq0, zf);
                zf = mfma_bf16(a1, bq1, zf);
                st[t] = zf;
            }
            __builtin_amdgcn_s_setprio(0);

            // p = 2^s (fixed m=0); mask only diagonal tile; l lane-local
            float p[16];
            if (kb == qb) {
                #pragma unroll
                for (int t = 0; t < 4; t++)
                    #pragma unroll
                    for (int i = 0; i < 4; i++) {
                        int kv = kb * 64 + t * 16 + 4 * g + i;
                        float e = fexp2(st[t][i]);
                        if (kv > qrow) e = 0.f;
                        p[t * 4 + i] = e;
                        l += e;
                    }
            } else {
                #pragma unroll
                for (int t = 0; t < 4; t++)
                    #pragma unroll
                    for (int i = 0; i < 4; i++) {
                        float e = fexp2(st[t][i]);
                        p[t * 4 + i] = e;
                        l += e;
                    }
            }

            // P fragments stay in registers: pd[t] = P[q=c][kv=t*16+4g..+3]
            i32x2 pd[4];
            #pragma unroll
            for (int t = 0; t < 4; t++) {
                pd[t][0] = cvtpk(p[t * 4 + 0], p[t * 4 + 1]);
                pd[t][1] = cvtpk(p[t * 4 + 2], p[t * 4 + 3]);
            }

            // PV via 16x16x16: acc[jt][q=4g+i][d=jt*16+c] += P[q][kv16]*V[kv16][d]
            __builtin_amdgcn_s_setprio(1);
            #pragma unroll
            for (int t = 0; t < 4; t++) {
                #pragma unroll
                for (int jt = 0; jt < 4; jt++) {
                    i32x2 vb = *(const i32x2*)&Vl[cur][jt * 16 + c][(t * 8 + 2 * g) ^ (4 * (c & 7))];
                    acc[jt] = mfma16_bf16(pd[t], vb, acc[jt]);
                }
            }
            __builtin_amdgcn_s_setprio(0);
        }

        // finalize: reduce l across g-groups (all lanes end with l(q=c))
        float lsum = l + __shfl_xor(l, 16);
        lsum += __shfl_xor(lsum, 32);
        if (SPLIT && lane < 16) {
            float Lv = (lsum > 0.f) ? __log2f(lsum) : -1e30f;
            Lf[(size_t)(z * 16 + h) * 4096 + (qb * 64 + w * 16 + lane)] = Lv;
        }
        float linv[4];
        #pragma unroll
        for (int i = 0; i < 4; i++) {
            float ls = __shfl(lsum, 4 * g + i);
            linv[i] = (ls > 0.f) ? 1.f / ls : 0.f;
        }
        #pragma unroll
        for (int jt = 0; jt < 4; jt++)
            #pragma unroll
            for (int i = 0; i < 4; i++) {
                int r = qb * 64 + w * 16 + 4 * g + i;
                O[(size_t)r * D + hc + jt * 16 + c] = f2bf(acc[jt][i] * linv[i]);
            }
    }
}

// ---------------------------------------------------------------------------
// Combine split-kv partials: Aw = w0*Aw + w1*P1, w_i = softmax over L.
// ---------------------------------------------------------------------------
__global__ __launch_bounds__(256) void combine_kernel(
    short* __restrict__ Aw, const short* __restrict__ P1, const float* __restrict__ Lf)
{
    const int t = blockIdx.x * 256 + threadIdx.x;
    const int idx = t * 8;
    const int row = idx >> 10, col = idx & 1023, h = col >> 6;
    float L0 = Lf[(size_t)h * 4096 + row];
    float L1 = Lf[(size_t)(16 + h) * 4096 + row];
    float LM = fmaxf(L0, L1);
    float w0 = fexp2(L0 - LM), w1 = fexp2(L1 - LM);
    float inv = 1.f / (w0 + w1);
    w0 *= inv; w1 *= inv;
    s16x8 a = *(s16x8*)(Aw + idx);
    s16x8 b = *(const s16x8*)(P1 + idx);
    s16x8 o;
    #pragma unroll
    for (int e = 0; e < 8; e++)
        o[e] = f2bf(w0 * bf2f(a[e]) + w1 * bf2f(b[e]));
    *(s16x8*)(Aw + idx) = o;
}

// ---------------------------------------------------------------------------
extern "C" void kernel_launch(void* const* d_in, const int* in_sizes, int n_in,
                              void* d_out, int out_size, void* d_ws, size_t ws_size,
                              hipStream_t stream)
{
    const float* x  = (const float*)d_in[0];
    const float* Wq = (const float*)d_in[1];
    const float* Wk = (const float*)d_in[2];
    const float* Wv = (const float*)d_in[3];
    const float* Wo = (const float*)d_in[4];
    const int*  pos = (const int*)d_in[5];
    float* out = (float*)d_out;

    const size_t SD = (size_t)4096 * 1024;
    const size_t WSZ = (size_t)1024 * 1024;
    short* Qw = (short*)d_ws;
    short* Kw = Qw + SD;
    short* Vw = Kw + SD;
    short* Aw = Vw + SD;

    const size_t need_A = (5 * SD + 4 * WSZ) * sizeof(short) + 2 * 16 * 4096 * sizeof(float);
    const size_t need_B = (4 * SD + 4 * WSZ) * sizeof(short);

    if (ws_size >= need_A) {
        short* P1  = Aw + SD;
        short* xb  = Aw;
        short* Wqb = P1 + SD;
        short* Wkb = Wqb + WSZ;
        short* Wvb = Wkb + WSZ;
        short* Wob = Wvb + WSZ;
        float* Lf  = (float*)(Wob + WSZ);
        conv_kernel<<<4096, 256, 0, stream>>>(x, Wq, Wk, Wv, Wo, xb, Wqb, Wkb, Wvb, Wob);
        gemm128<128, 1, 1><<<dim3(8, 32, 3), 256, 0, stream>>>(xb, Wqb, Wkb, Wvb, Qw, Kw, Vw, pos);
        attn_kernel<1><<<1024, 256, 0, stream>>>(Qw, Kw, Vw, Aw, P1, Lf);
        combine_kernel<<<2048, 256, 0, stream>>>(Aw, P1, Lf);
        gemm128<64, 0, 0><<<dim3(8, 64, 1), 256, 0, stream>>>(Aw, Wob, Wob, Wob, out, out, out, pos);
    } else if (ws_size >= need_B) {
        short* xb  = Aw;
        short* Wqb = Aw + SD;
        short* Wkb = Wqb + WSZ;
        short* Wvb = Wkb + WSZ;
        short* Wob = Wvb + WSZ;
        conv_kernel<<<4096, 256, 0, stream>>>(x, Wq, Wk, Wv, Wo, xb, Wqb, Wkb, Wvb, Wob);
        gemm128<128, 1, 1><<<dim3(8, 32, 3), 256, 0, stream>>>(xb, Wqb, Wkb, Wvb, Qw, Kw, Vw, pos);
        attn_kernel<0><<<dim3(32, 16, 1), 256, 0, stream>>>(Qw, Kw, Vw, Aw, Aw, nullptr);
        gemm128<64, 0, 0><<<dim3(8, 64, 1), 256, 0, stream>>>(Aw, Wob, Wob, Wob, out, out, out, pos);
    } else {
        gemm_bt<0, 1><<<dim3(16, 64, 3), 256, 0, stream>>>(x, Wq, Wk, Wv, Qw, Kw, Vw);
        rope_kernel<<<dim3(2048, 2), 256, 0, stream>>>(Qw, Kw, pos);
        attn_kernel<0><<<dim3(32, 16, 1), 256, 0, stream>>>(Qw, Kw, Vw, Aw, Aw, nullptr);
        gemm_bt<1, 0><<<dim3(16, 64, 1), 256, 0, stream>>>(Aw, Wo, Wo, Wo, out, out, out);
    }
}

// Round 8
// 131.182 us; speedup vs baseline: 1.3306x; 1.0596x over previous
//
#include <hip/hip_runtime.h>

typedef float f32x4 __attribute__((ext_vector_type(4)));
typedef short s16x8 __attribute__((ext_vector_type(8)));
typedef int   i32x2 __attribute__((ext_vector_type(2)));
typedef int   i32x4 __attribute__((ext_vector_type(4)));

#define DEV static __device__ __forceinline__

DEV short f2bf(float f) {
    unsigned u = __builtin_bit_cast(unsigned, f);
    u += 0x7FFFu + ((u >> 16) & 1u);
    return (short)(u >> 16);
}
DEV float bf2f(short s) {
    return __builtin_bit_cast(float, ((unsigned)(unsigned short)s) << 16);
}
DEV int cvtpk(float lo, float hi) {
    int r;
    asm("v_cvt_pk_bf16_f32 %0, %1, %2" : "=v"(r) : "v"(lo), "v"(hi));
    return r;
}
DEV float fexp2(float x) { float r; asm("v_exp_f32 %0, %1" : "=v"(r) : "v"(x)); return r; }
DEV float ffract(float x){ float r; asm("v_fract_f32 %0, %1" : "=v"(r) : "v"(x)); return r; }
DEV float fsin(float x)  { float r; asm("v_sin_f32 %0, %1" : "=v"(r) : "v"(x)); return r; }
DEV float fcos(float x)  { float r; asm("v_cos_f32 %0, %1" : "=v"(r) : "v"(x)); return r; }
DEV f32x4 mfma_bf16(s16x8 a, s16x8 b, f32x4 c) {
    asm("v_mfma_f32_16x16x32_bf16 %0, %1, %2, %0" : "+v"(c) : "v"(a), "v"(b));
    return c;
}
DEV f32x4 mfma16_bf16(i32x2 a, i32x2 b, f32x4 c) {
    asm("v_mfma_f32_16x16x16_bf16 %0, %1, %2, %0" : "+v"(c) : "v"(a), "v"(b));
    return c;
}
DEV void gl_lds16(const void* g, void* l) {
    __builtin_amdgcn_global_load_lds((const __attribute__((address_space(1))) unsigned*)g,
                                     (__attribute__((address_space(3))) unsigned*)l, 16, 0, 0);
}

// ---------------------------------------------------------------------------
// f32 -> bf16 convert: x (4M elems) + 4 weights (1M each).
// ---------------------------------------------------------------------------
__global__ __launch_bounds__(256) void conv_kernel(
    const float* __restrict__ x,
    const float* __restrict__ W0, const float* __restrict__ W1,
    const float* __restrict__ W2, const float* __restrict__ W3,
    short* __restrict__ xb,
    short* __restrict__ B0, short* __restrict__ B1,
    short* __restrict__ B2, short* __restrict__ B3)
{
    const int bid = blockIdx.x, tid = threadIdx.x;
    const float* src;
    short* dst;
    size_t off;
    if (bid < 2048) {
        src = x; dst = xb; off = (size_t)bid * 2048 + tid * 8;
    } else {
        int t = bid - 2048, wi = t >> 9;
        src = wi == 0 ? W0 : (wi == 1 ? W1 : (wi == 2 ? W2 : W3));
        dst = wi == 0 ? B0 : (wi == 1 ? B1 : (wi == 2 ? B2 : B3));
        off = (size_t)(t & 511) * 2048 + tid * 8;
    }
    f32x4 v0 = *(const f32x4*)(src + off);
    f32x4 v1 = *(const f32x4*)(src + off + 4);
    s16x8 o;
    #pragma unroll
    for (int e = 0; e < 4; e++) { o[e] = f2bf(v0[e]); o[4 + e] = f2bf(v1[e]); }
    *(s16x8*)(dst + off) = o;
}

// ---------------------------------------------------------------------------
// m97-structure GEMM: C[M][N] = A[M][1024] * B[N][1024]^T, bf16 inputs.
// BM = 128 or 64. ROPE=1: fused rope epilogue, z<=1; Q gets log2(e)/8 fold.
// ---------------------------------------------------------------------------
template<int BM, int OUT_BF16, int ROPE>
__global__ __launch_bounds__(256) void gemm128(
    const short* __restrict__ A,
    const short* __restrict__ Bq, const short* __restrict__ Bk, const short* __restrict__ Bv,
    void* __restrict__ Cq, void* __restrict__ Ck, void* __restrict__ Cv,
    const int* __restrict__ posp)
{
    constexpr int KD = 1024, ND = 1024;
    constexpr int MI = BM / 32;
    __shared__ __align__(16) short As[BM * 32];
    __shared__ __align__(16) short Bs[128 * 32];
    const int n0 = blockIdx.x * 128, m0 = blockIdx.y * BM;
    const int zz = blockIdx.z;
    const short* B = zz == 0 ? Bq : (zz == 1 ? Bk : Bv);
    void* C       = zz == 0 ? Cq : (zz == 1 ? Ck : Cv);
    const int tid = threadIdx.x;
    const int lane = tid & 63, w = tid >> 6, g = lane >> 4, c = lane & 15;
    const int wm = w >> 1, wn = w & 1;

    const int swz = (tid & 3) ^ ((tid >> 3) & 3);
    const short* a0 = A + (size_t)(m0 + (tid >> 2)) * KD + 8 * swz;
    const short* a1 = a0 + (size_t)64 * KD;
    const short* b0 = B + (size_t)(n0 + (tid >> 2)) * KD + 8 * swz;
    const short* b1 = b0 + (size_t)64 * KD;
    char* ldsA = (char*)As + w * 1024;
    char* ldsB = (char*)Bs + w * 1024;

    int aoff[MI], boff[4];
    #pragma unroll
    for (int i = 0; i < MI; i++) {
        int ar = wm * (BM / 2) + i * 16 + c;
        aoff[i] = ar * 64 + (g ^ ((ar >> 1) & 3)) * 16;
    }
    #pragma unroll
    for (int j = 0; j < 4; j++) {
        int br = wn * 64 + j * 16 + c;
        boff[j] = br * 64 + (g ^ ((br >> 1) & 3)) * 16;
    }

    f32x4 acc[MI][4] = {};

    for (int k0 = 0; k0 < KD; k0 += 32) {
        __syncthreads();
        gl_lds16(a0 + k0, ldsA);
        if (BM == 128) gl_lds16(a1 + k0, ldsA + 4096);
        gl_lds16(b0 + k0, ldsB);
        gl_lds16(b1 + k0, ldsB + 4096);
        __syncthreads();
        s16x8 af[MI], bf[4];
        #pragma unroll
        for (int i = 0; i < MI; i++) af[i] = *(const s16x8*)((const char*)As + aoff[i]);
        #pragma unroll
        for (int j = 0; j < 4; j++) bf[j] = *(const s16x8*)((const char*)Bs + boff[j]);
        #pragma unroll
        for (int i = 0; i < MI; i++)
            #pragma unroll
            for (int j = 0; j < 4; j++)
                acc[i][j] = mfma_bf16(af[i], bf[j], acc[i][j]);
    }

    if (ROPE && zz <= 1) {
        const float ps = (zz == 0) ? 0.18033688011112042f : 1.0f;
        #pragma unroll
        for (int j = 0; j < 4; j++) {
            int col = n0 + wn * 64 + j * 16 + c;
            float invf = fexp2(-(float)((col & 63) >> 1) * 0.51905126482615036f)
                       * 0.15915494309189535f;
            float ssign = (col & 1) ? 1.f : -1.f;
            #pragma unroll
            for (int i = 0; i < MI; i++)
                #pragma unroll
                for (int r = 0; r < 4; r++) {
                    int row = m0 + wm * (BM / 2) + i * 16 + 4 * g + r;
                    float fp = (float)posp[row];
                    float fr = ffract(fp * invf);
                    float sn = fsin(fr) * ps, cs = fcos(fr) * ps;
                    float own = acc[i][j][r];
                    float oth = __shfl_xor(own, 1);
                    acc[i][j][r] = own * cs + oth * (ssign * sn);
                }
        }
    }

    #pragma unroll
    for (int i = 0; i < MI; i++)
        #pragma unroll
        for (int j = 0; j < 4; j++)
            #pragma unroll
            for (int r = 0; r < 4; r++) {
                int row = m0 + wm * (BM / 2) + i * 16 + 4 * g + r;
                int col = n0 + wn * 64 + j * 16 + c;
                float v = acc[i][j][r];
                if (OUT_BF16) ((short*)C)[(size_t)row * ND + col] = f2bf(v);
                else          ((float*)C)[(size_t)row * ND + col] = v;
            }
}

// ---------------------------------------------------------------------------
// fallback GEMM (f32 inputs, 64x64 tile)
// ---------------------------------------------------------------------------
template<int A_BF16, int OUT_BF16>
__global__ __launch_bounds__(256) void gemm_bt(
    const void* __restrict__ Ap,
    const float* __restrict__ B0, const float* __restrict__ B1, const float* __restrict__ B2,
    void* __restrict__ C0, void* __restrict__ C1, void* __restrict__ C2)
{
    constexpr int KD = 1024, ND = 1024;
    __shared__ short As[64][40];
    __shared__ short Bs[64][40];
    const int n0 = blockIdx.x * 64, m0 = blockIdx.y * 64;
    const float* Bw = blockIdx.z == 0 ? B0 : (blockIdx.z == 1 ? B1 : B2);
    void* Cw       = blockIdx.z == 0 ? C0 : (blockIdx.z == 1 ? C1 : C2);
    const int tid = threadIdx.x;
    const int lane = tid & 63, w = tid >> 6, g = lane >> 4, c = lane & 15;
    const int wm = w >> 1, wn = w & 1;
    const int sr = tid >> 2, scc = (tid & 3) * 8;

    f32x4 acc[2][2] = {};

    for (int k0 = 0; k0 < KD; k0 += 32) {
        __syncthreads();
        if (A_BF16) {
            *(s16x8*)&As[sr][scc] =
                *(const s16x8*)((const short*)Ap + (size_t)(m0 + sr) * KD + k0 + scc);
        } else {
            const float* ap = (const float*)Ap + (size_t)(m0 + sr) * KD + k0 + scc;
            f32x4 va = *(const f32x4*)ap, vb = *(const f32x4*)(ap + 4);
            s16x8 av;
            #pragma unroll
            for (int e = 0; e < 4; e++) { av[e] = f2bf(va[e]); av[4 + e] = f2bf(vb[e]); }
            *(s16x8*)&As[sr][scc] = av;
        }
        {
            const float* bp = Bw + (size_t)(n0 + sr) * KD + k0 + scc;
            f32x4 va = *(const f32x4*)bp, vb = *(const f32x4*)(bp + 4);
            s16x8 bv;
            #pragma unroll
            for (int e = 0; e < 4; e++) { bv[e] = f2bf(va[e]); bv[4 + e] = f2bf(vb[e]); }
            *(s16x8*)&Bs[sr][scc] = bv;
        }
        __syncthreads();
        s16x8 af[2], bfv[2];
        #pragma unroll
        for (int i = 0; i < 2; i++) af[i]  = *(const s16x8*)&As[wm * 32 + i * 16 + c][8 * g];
        #pragma unroll
        for (int j = 0; j < 2; j++) bfv[j] = *(const s16x8*)&Bs[wn * 32 + j * 16 + c][8 * g];
        #pragma unroll
        for (int i = 0; i < 2; i++)
            #pragma unroll
            for (int j = 0; j < 2; j++)
                acc[i][j] = mfma_bf16(af[i], bfv[j], acc[i][j]);
    }

    #pragma unroll
    for (int i = 0; i < 2; i++)
        #pragma unroll
        for (int j = 0; j < 2; j++)
            #pragma unroll
            for (int r = 0; r < 4; r++) {
                int row = m0 + wm * 32 + i * 16 + 4 * g + r;
                int col = n0 + wn * 32 + j * 16 + c;
                float v = acc[i][j][r];
                if (OUT_BF16) ((short*)Cw)[(size_t)row * ND + col] = f2bf(v);
                else          ((float*)Cw)[(size_t)row * ND + col] = v;
            }
}

// ---------------------------------------------------------------------------
// standalone RoPE (fallback tier only)
// ---------------------------------------------------------------------------
__global__ __launch_bounds__(256) void rope_kernel(short* Q, short* K, const int* __restrict__ posp)
{
    const int t = blockIdx.x * 256 + threadIdx.x;
    const int isK = blockIdx.y;
    short* ptr = isK ? K : Q;
    const float postscale = isK ? 1.0f : 0.18033688011112042f;
    const int idx  = t * 8;
    const int srow = idx >> 10;
    const int dd   = (idx & 1023) & 63;
    const int p0   = dd >> 1;
    const float fp = (float)posp[srow];
    s16x8 v = *(s16x8*)(ptr + idx);
    s16x8 o;
    #pragma unroll
    for (int pr = 0; pr < 4; pr++) {
        float ex  = fexp2(-(float)(p0 + pr) * 0.51905126482615036f);
        float ang = fp * ex * 0.15915494309189535f;
        float fr  = ffract(ang);
        float sn  = fsin(fr) * postscale;
        float cs  = fcos(fr) * postscale;
        float x1 = bf2f(v[2 * pr]), x2 = bf2f(v[2 * pr + 1]);
        o[2 * pr]     = f2bf(x1 * cs - x2 * sn);
        o[2 * pr + 1] = f2bf(x1 * sn + x2 * cs);
    }
    *(s16x8*)(ptr + idx) = o;
}

// ---------------------------------------------------------------------------
// Flash attention v8: 8 waves (512 thr), QBLK=128 (wave w owns 16 q-rows of a
// 128-row q-tile) -> K/V staging, barriers, vmcnt drains amortized over 2x
// q-rows. Waves 0-3 stage K (gl_lds, pre-swizzled src); waves 4-7 stage V
// (reg pack). q-tiles paired {qx, 31-qx} sequentially; SPLIT: kv strided by 2
// (uniform 33 iters); XCD head pinning (head h -> XCD h%8).
// Fixed-m softmax (log2-domain scores); P in registers (16x16x16 PV).
// ---------------------------------------------------------------------------
template<int SPLIT>
__global__ __launch_bounds__(512, 2) void attn_kernel(
    const short* __restrict__ Q, const short* __restrict__ K,
    const short* __restrict__ V, short* __restrict__ O0,
    short* __restrict__ O1, float* __restrict__ Lf)
{
    constexpr int D = 1024;
    constexpr int ST = 1 + SPLIT;
    int qx, h, z;
    if (SPLIT) {
        const int B = blockIdx.x;           // 512 blocks
        const int xcd = B & 7, k = B >> 3;  // k 0..63
        h = xcd + 8 * (k >> 5);
        const int r = k & 31;
        qx = r & 15;
        z = r >> 4;
    } else {
        qx = blockIdx.x; h = blockIdx.y; z = 0;
    }
    const int hc = h * 64;
    short* O = (SPLIT && z) ? O1 : O0;
    const int tid = threadIdx.x;
    const int w = tid >> 6, lane = tid & 63, g = lane >> 4, c = lane & 15;

    __shared__ __align__(16) int Kl[2][64 * 32];  // 64x64 bf16, chunk^=(row&7)
    __shared__ __align__(16) int Vl[2][64][32];   // [d][kvp] dwords, chunk^=(d&7)

    // K staging (waves 0-3): wave wk rows wk*16..+15, 2 passes of 8 rows
    const int wk = w & 3;
    const int krow_l = lane >> 3;
    const int kchunk = (lane & 7) ^ krow_l;
    const short* Kpre = K + hc + (size_t)(wk * 16 + krow_l) * D + kchunk * 8;
    char* kdst0 = (char*)&Kl[0][0] + wk * 16 * 128;
    char* kdst1 = (char*)&Kl[1][0] + wk * 16 * 128;

    // V staging (waves 4-7): 256 threads pack pairs along kv
    const int vtid = tid & 255;
    const int vkvp = vtid & 31;
    const int vd0 = (vtid >> 5) * 8;
    const short* Vpre = V + hc + (size_t)(2 * vkvp) * D + vd0;

    int koff0[4], koff1[4];
    #pragma unroll
    for (int t = 0; t < 4; t++) {
        int row = t * 16 + c;
        koff0[t] = row * 128 + ((g) ^ (row & 7)) * 16;
        koff1[t] = row * 128 + ((4 + g) ^ (row & 7)) * 16;
    }

    for (int pi = 0; pi < 2; pi++) {
        const int qq = pi ? 31 - qx : qx;
        const int wq_min = qq * 128 + w * 16;      // min q-row in this wave
        const int qrow = wq_min + c;
        const short* qp = Q + (size_t)qrow * D + hc + 8 * g;
        const s16x8 bq0 = *(const s16x8*)qp;
        const s16x8 bq1 = *(const s16x8*)(qp + 32);

        f32x4 acc[4] = {};
        float l = 0.f;
        const int nkb = 2 * qq + 2;

        __syncthreads();   // prev pi's LDS reads fully done
        s16x8 vs0, vs1;
        {   // prologue: stage tile kb=z into buffer 0
            if (w < 4) {
                gl_lds16(Kpre + (size_t)(z * 64) * D, kdst0);
                gl_lds16(Kpre + (size_t)(z * 64 + 8) * D, kdst0 + 8 * 128);
            } else {
                const short* vp = Vpre + (size_t)(z * 64) * D;
                vs0 = *(const s16x8*)vp;
                vs1 = *(const s16x8*)(vp + D);
            }
        }

        int cur = 0;
        for (int kb = z; kb < nkb; kb += ST, cur ^= 1) {
            // waves 4-7: pack V (tile kb) into Vl[cur]
            if (w >= 4) {
                #pragma unroll
                for (int e = 0; e < 8; e++) {
                    unsigned dw = (unsigned)(unsigned short)vs0[e] | ((unsigned)(unsigned short)vs1[e] << 16);
                    Vl[cur][vd0 + e][vkvp ^ (4 * e)] = (int)dw;
                }
            }
            asm volatile("s_waitcnt vmcnt(0)" ::: "memory");   // own K gl_lds landed
            __syncthreads();

            // issue next-tile staging (targets buffer cur^1)
            const bool more = (kb + ST) < nkb;
            if (more) {
                const int kb1 = kb + ST;
                if (w < 4) {
                    char* kd = cur ? kdst0 : kdst1;
                    gl_lds16(Kpre + (size_t)(kb1 * 64) * D, kd);
                    gl_lds16(Kpre + (size_t)(kb1 * 64 + 8) * D, kd + 8 * 128);
                } else {
                    const short* vp = Vpre + (size_t)(kb1 * 64) * D;
                    vs0 = *(const s16x8*)vp;
                    vs1 = *(const s16x8*)(vp + D);
                }
            }

            // wave-uniform activity: skip if every q-row of this wave < kv tile
            if (kb * 64 > wq_min + 15) continue;

            // QK^T (swapped): st[t][i] = S[kv = kb*64+t*16+4g+i][q = qrow]
            const char* Kb = (const char*)&Kl[cur][0];
            f32x4 st[4];
            __builtin_amdgcn_s_setprio(1);
            #pragma unroll
            for (int t = 0; t < 4; t++) {
                s16x8 a0 = *(const s16x8*)(Kb + koff0[t]);
                s16x8 a1 = *(const s16x8*)(Kb + koff1[t]);
                f32x4 zf = {};
                zf = mfma_bf16(a0, bq0, zf);
                zf = mfma_bf16(a1, bq1, zf);
                st[t] = zf;
            }
            __builtin_amdgcn_s_setprio(0);

            // p = 2^s (fixed m=0); mask only tiles overlapping the diagonal
            float p[16];
            if (kb * 64 + 63 > wq_min) {
                #pragma unroll
                for (int t = 0; t < 4; t++)
                    #pragma unroll
                    for (int i = 0; i < 4; i++) {
                        int kv = kb * 64 + t * 16 + 4 * g + i;
                        float e = fexp2(st[t][i]);
                        if (kv > qrow) e = 0.f;
                        p[t * 4 + i] = e;
                        l += e;
                    }
            } else {
                #pragma unroll
                for (int t = 0; t < 4; t++)
                    #pragma unroll
                    for (int i = 0; i < 4; i++) {
                        float e = fexp2(st[t][i]);
                        p[t * 4 + i] = e;
                        l += e;
                    }
            }

            // P fragments in registers: pd[t] = P[q=c][kv=t*16+4g..+3]
            i32x2 pd[4];
            #pragma unroll
            for (int t = 0; t < 4; t++) {
                pd[t][0] = cvtpk(p[t * 4 + 0], p[t * 4 + 1]);
                pd[t][1] = cvtpk(p[t * 4 + 2], p[t * 4 + 3]);
            }

            // PV via 16x16x16: acc[jt][q=4g+i][d=jt*16+c] += P[q][kv16]*V[kv16][d]
            __builtin_amdgcn_s_setprio(1);
            #pragma unroll
            for (int t = 0; t < 4; t++) {
                #pragma unroll
                for (int jt = 0; jt < 4; jt++) {
                    i32x2 vb = *(const i32x2*)&Vl[cur][jt * 16 + c][(t * 8 + 2 * g) ^ (4 * (c & 7))];
                    acc[jt] = mfma16_bf16(pd[t], vb, acc[jt]);
                }
            }
            __builtin_amdgcn_s_setprio(0);
        }

        // finalize: reduce l across g-groups (all lanes end with l(q=c))
        float lsum = l + __shfl_xor(l, 16);
        lsum += __shfl_xor(lsum, 32);
        if (SPLIT && lane < 16) {
            float Lv = (lsum > 0.f) ? __log2f(lsum) : -1e30f;
            Lf[(size_t)(z * 16 + h) * 4096 + (qq * 128 + w * 16 + lane)] = Lv;
        }
        float linv[4];
        #pragma unroll
        for (int i = 0; i < 4; i++) {
            float ls = __shfl(lsum, 4 * g + i);
            linv[i] = (ls > 0.f) ? 1.f / ls : 0.f;
        }
        #pragma unroll
        for (int jt = 0; jt < 4; jt++)
            #pragma unroll
            for (int i = 0; i < 4; i++) {
                int r = qq * 128 + w * 16 + 4 * g + i;
                O[(size_t)r * D + hc + jt * 16 + c] = f2bf(acc[jt][i] * linv[i]);
            }
    }
}

// ---------------------------------------------------------------------------
// Combine split-kv partials: Aw = w0*Aw + w1*P1, w_i = softmax over L.
// ---------------------------------------------------------------------------
__global__ __launch_bounds__(256) void combine_kernel(
    short* __restrict__ Aw, const short* __restrict__ P1, const float* __restrict__ Lf)
{
    const int t = blockIdx.x * 256 + threadIdx.x;
    const int idx = t * 8;
    const int row = idx >> 10, col = idx & 1023, h = col >> 6;
    float L0 = Lf[(size_t)h * 4096 + row];
    float L1 = Lf[(size_t)(16 + h) * 4096 + row];
    float LM = fmaxf(L0, L1);
    float w0 = fexp2(L0 - LM), w1 = fexp2(L1 - LM);
    float inv = 1.f / (w0 + w1);
    w0 *= inv; w1 *= inv;
    s16x8 a = *(s16x8*)(Aw + idx);
    s16x8 b = *(const s16x8*)(P1 + idx);
    s16x8 o;
    #pragma unroll
    for (int e = 0; e < 8; e++)
        o[e] = f2bf(w0 * bf2f(a[e]) + w1 * bf2f(b[e]));
    *(s16x8*)(Aw + idx) = o;
}

// ---------------------------------------------------------------------------
extern "C" void kernel_launch(void* const* d_in, const int* in_sizes, int n_in,
                              void* d_out, int out_size, void* d_ws, size_t ws_size,
                              hipStream_t stream)
{
    const float* x  = (const float*)d_in[0];
    const float* Wq = (const float*)d_in[1];
    const float* Wk = (const float*)d_in[2];
    const float* Wv = (const float*)d_in[3];
    const float* Wo = (const float*)d_in[4];
    const int*  pos = (const int*)d_in[5];
    float* out = (float*)d_out;

    const size_t SD = (size_t)4096 * 1024;
    const size_t WSZ = (size_t)1024 * 1024;
    short* Qw = (short*)d_ws;
    short* Kw = Qw + SD;
    short* Vw = Kw + SD;
    short* Aw = Vw + SD;

    const size_t need_A = (5 * SD + 4 * WSZ) * sizeof(short) + 2 * 16 * 4096 * sizeof(float);
    const size_t need_B = (4 * SD + 4 * WSZ) * sizeof(short);

    if (ws_size >= need_A) {
        short* P1  = Aw + SD;
        short* xb  = Aw;
        short* Wqb = P1 + SD;
        short* Wkb = Wqb + WSZ;
        short* Wvb = Wkb + WSZ;
        short* Wob = Wvb + WSZ;
        float* Lf  = (float*)(Wob + WSZ);
        conv_kernel<<<4096, 256, 0, stream>>>(x, Wq, Wk, Wv, Wo, xb, Wqb, Wkb, Wvb, Wob);
        gemm128<128, 1, 1><<<dim3(8, 32, 3), 256, 0, stream>>>(xb, Wqb, Wkb, Wvb, Qw, Kw, Vw, pos);
        attn_kernel<1><<<512, 512, 0, stream>>>(Qw, Kw, Vw, Aw, P1, Lf);
        combine_kernel<<<2048, 256, 0, stream>>>(Aw, P1, Lf);
        gemm128<64, 0, 0><<<dim3(8, 64, 1), 256, 0, stream>>>(Aw, Wob, Wob, Wob, out, out, out, pos);
    } else if (ws_size >= need_B) {
        short* xb  = Aw;
        short* Wqb = Aw + SD;
        short* Wkb = Wqb + WSZ;
        short* Wvb = Wkb + WSZ;
        short* Wob = Wvb + WSZ;
        conv_kernel<<<4096, 256, 0, stream>>>(x, Wq, Wk, Wv, Wo, xb, Wqb, Wkb, Wvb, Wob);
        gemm128<128, 1, 1><<<dim3(8, 32, 3), 256, 0, stream>>>(xb, Wqb, Wkb, Wvb, Qw, Kw, Vw, pos);
        attn_kernel<0><<<dim3(16, 16, 1), 512, 0, stream>>>(Qw, Kw, Vw, Aw, Aw, nullptr);
        gemm128<64, 0, 0><<<dim3(8, 64, 1), 256, 0, stream>>>(Aw, Wob, Wob, Wob, out, out, out, pos);
    } else {
        gemm_bt<0, 1><<<dim3(16, 64, 3), 256, 0, stream>>>(x, Wq, Wk, Wv, Qw, Kw, Vw);
        rope_kernel<<<dim3(2048, 2), 256, 0, stream>>>(Qw, Kw, pos);
        attn_kernel<0><<<dim3(16, 16, 1), 512, 0, stream>>>(Qw, Kw, Vw, Aw, Aw, nullptr);
        gemm_bt<1, 0><<<dim3(16, 64, 1), 256, 0, stream>>>(Aw, Wo, Wo, Wo, out, out, out);
    }
}